// Round 8
// baseline (207.402 us; speedup 1.0000x reference)
//
#include <hip/hip_runtime.h>
#include <stdint.h>

using i32x4  = __attribute__((ext_vector_type(4)))  int;
using i32x16 = __attribute__((ext_vector_type(16))) int;

#define M_TOT 8192
#define N_TOT 4096
#define K_TOT 4096
#define BM 256
#define BN 128
// BK = 64 bytes; 64 K-intervals; LDS ring-3 (A 3x16KB | B 3x8KB = 72KB)
// => 2 independent blocks/CU (the R7 post-mortem lever: cross-block overlap)

__device__ __forceinline__ void gload_lds16(const void* g, void* l) {
  __builtin_amdgcn_global_load_lds(
      (const __attribute__((address_space(1))) void*)(uintptr_t)g,
      (__attribute__((address_space(3))) void*)(uint32_t)(uintptr_t)l,
      16, 0, 0);
}

// Repack int32-widened int8 [rows][4096] into swizzled K-chunk tiles:
// chunk (p,kc) = 16KB: [rr 0..255][64B]; physical 16B-slot sp holds logical
// slot sp ^ ((rr>>1)&3).  GEMM staging is a pure linear copy (rule #21) and
// the frag ds_read applies the same XOR: 8 lanes per 4-bank quad, all 8
// quads parallel -> throughput-optimal (the residual 4cy/instr counter is
// intrinsic wave64-b128 overhead, constant across layouts R4-R7).
__global__ void pack_tiles(const int* __restrict__ a32, const int* __restrict__ b32,
                           int8_t* __restrict__ ap, int8_t* __restrict__ bp,
                           int na, int ntot) {
  int stride = gridDim.x * blockDim.x;
  for (int idx = blockIdx.x * blockDim.x + threadIdx.x; idx < ntot; idx += stride) {
    int i = idx;
    const int* src;
    int8_t* dst;
    if (idx < na) { src = a32; dst = ap; }
    else          { src = b32; dst = bp; i = idx - na; }
    int sp = i & 3;
    int rr = (i >> 2) & 255;
    int kc = (i >> 10) & 63;
    int p  = i >> 16;
    int sl = sp ^ ((rr >> 1) & 3);
    const i32x4* s = (const i32x4*)(src + (((size_t)(p * 256 + rr)) << 12) + kc * 64 + sl * 16);
    i32x4 a = s[0], b = s[1], c = s[2], d = s[3];
    i32x4 o;
    o.x = (a.x & 255) | ((a.y & 255) << 8) | ((a.z & 255) << 16) | (a.w << 24);
    o.y = (b.x & 255) | ((b.y & 255) << 8) | ((b.z & 255) << 16) | (b.w << 24);
    o.z = (c.x & 255) | ((c.y & 255) << 8) | ((c.z & 255) << 16) | (c.w << 24);
    o.w = (d.x & 255) | ((d.y & 255) << 8) | ((d.z & 255) << 16) | (d.w << 24);
    ((i32x4*)dst)[i] = o;
  }
}

// stage chunk kc into ring region R: A 16KB (wave w: 4KB), B 8KB (wave w: 2KB)
#define STAGE(kc, R) {                                                     \
    const int8_t* _ga = Asrc + (size_t)(kc) * 16384 + w * 4096 + l * 16;   \
    char* _da = lds + (R) * 16384 + w * 4096 + l * 16;                     \
    gload_lds16(_ga, _da);               gload_lds16(_ga + 1024, _da + 1024); \
    gload_lds16(_ga + 2048, _da + 2048); gload_lds16(_ga + 3072, _da + 3072); \
    const int8_t* _gb = Bsrc + (size_t)(kc) * 16384 + w * 2048 + l * 16;   \
    char* _db = lds + 49152 + (R) * 8192 + w * 2048 + l * 16;              \
    gload_lds16(_gb, _db);               gload_lds16(_gb + 1024, _db + 1024); }

// frag read for K-step S (0..1) from ring region R
#define LOAD_FRAGS(DA, DB, R, S) {                                          \
    const int _so = ((((S) << 1) | hi) ^ swz) * 16;                         \
    const char* _pa = lds + (R) * 16384 + _so;                              \
    const char* _pb = lds + 49152 + (R) * 8192 + _so;                       \
    _Pragma("unroll")                                                       \
    for (int mi = 0; mi < 4; ++mi) DA[mi] = *(const i32x4*)(_pa + aRow[mi]); \
    _Pragma("unroll")                                                       \
    for (int ni = 0; ni < 2; ++ni) DB[ni] = *(const i32x4*)(_pb + bRow[ni]); }

#define MFMA8(A, B)                                                         \
    _Pragma("unroll")                                                       \
    for (int mi = 0; mi < 4; ++mi)                                          \
    _Pragma("unroll")                                                       \
    for (int ni = 0; ni < 2; ++ni)                                          \
      acc[mi][ni] = __builtin_amdgcn_mfma_i32_32x32x32_i8(A[mi], B[ni], acc[mi][ni], 0, 0, 0);

#define SGB(m, n) __builtin_amdgcn_sched_group_barrier((m), (n), 0)
#define PAIR SGB(0x8, 1); SGB(0x100, 1);

// Interval j: compute ring region R = j%3; stage chunk j+2 into (j+2)%3.
// Entry vmcnt(6) retires stage(j) while stage(j+1)'s 6 loads stay in flight
// (counted, never 0 until the tail).  Odd waves run K-steps in reverse
// order (int32 accum is exact) to anti-phase the LDS/MFMA bursts.
#define INTERVAL(kc2, R, RS, VM, DO_STAGE) {                                \
    asm volatile("s_waitcnt vmcnt(" VM ")" ::: "memory");                   \
    __builtin_amdgcn_s_barrier();                                           \
    __builtin_amdgcn_sched_barrier(0);                                      \
    __builtin_amdgcn_s_setprio(1);                                          \
    if (DO_STAGE) STAGE(kc2, RS)                                            \
    LOAD_FRAGS(a0, b0, R, sf)                                               \
    MFMA8(a0, b0)                                                           \
    LOAD_FRAGS(a1, b1, R, ss)                                               \
    MFMA8(a1, b1)                                                           \
    SGB(0x100, 6);                                                          \
    SGB(0x10, 6);                                                           \
    PAIR PAIR PAIR PAIR PAIR PAIR                                           \
    SGB(0x8, 10);                                                           \
    __builtin_amdgcn_s_setprio(0); }

__global__ __launch_bounds__(256, 2) void gemm_w8a8(
    const int8_t* __restrict__ Apack,  // [32 pm][64 kc][256 r][64B] swizzled
    const int8_t* __restrict__ Bpack,  // [16 pn][64 kc][256 r][64B] swizzled
    const int*    __restrict__ bias,
    const float*  __restrict__ alphap,
    const float*  __restrict__ betap,
    int* __restrict__ out)             // [M][N] int32
{
  __shared__ __align__(16) char lds[73728];  // A: 3x16KB @0 | B: 3x8KB @48KB

  // XCD-aware chunking: 1024 blocks, xcd = bid&7; per XCD 8 tm x 16 tn
  const int bid = blockIdx.x;
  const int xcd = bid & 7, wi = bid >> 3;
  const int tm = (xcd & 3) * 8 + (wi & 7);     // 0..31  (M/256)
  const int tn = (xcd >> 2) * 16 + (wi >> 3);  // 0..31  (N/128)

  const int tid = threadIdx.x;
  const int w   = tid >> 6;   // 4 waves
  const int l   = tid & 63;
  const int lr  = l & 31;
  const int hi  = l >> 5;
  const int wr  = w >> 1;     // 0..1
  const int wc  = w & 1;      // 0..1
  const int sf  = w & 1;      // K-step order: odd waves reversed (anti-phase)
  const int ss  = sf ^ 1;

  const int8_t* Asrc = Apack + ((size_t)tm << 20);                    // 1MB panels
  const int8_t* Bsrc = Bpack + ((size_t)(tn >> 1) << 20) + (tn & 1) * 8192;

  const int swz = (lr >> 1) & 3;
  int aRow[4], bRow[2];
#pragma unroll
  for (int mi = 0; mi < 4; ++mi) aRow[mi] = (wr * 128 + mi * 32 + lr) * 64;
#pragma unroll
  for (int ni = 0; ni < 2; ++ni) bRow[ni] = (wc * 64 + ni * 32 + lr) * 64;

  i32x16 acc[4][2] = {};
  i32x4 a0[4], b0[2], a1[4], b1[2];

  // prologue: stages 0,1 in flight (12 loads)
  STAGE(0, 0)
  STAGE(1, 1)

  // intervals j = 0..59 (20 x 3-unrolled ring)
  for (int t = 0; t < 20; ++t) {
    const int j = t * 3;
    INTERVAL(j + 2, 0, 2, "6", 1)
    INTERVAL(j + 3, 1, 0, "6", 1)
    INTERVAL(j + 4, 2, 1, "6", 1)
  }
  // tail: j=60 (stage 62), 61 (stage 63), 62 (none), 63 (drain)
  INTERVAL(62, 0, 2, "6", 1)
  INTERVAL(63, 1, 0, "6", 1)
  INTERVAL(0,  2, 0, "6", 0)
  INTERVAL(0,  0, 0, "0", 0)

  // epilogue: y = clip(rint(alpha*acc + beta*bias)) -> int32
  // C/D 32x32 layout: col = lane&31, row = (reg&3) + 8*(reg>>2) + 4*(lane>>5)
  const float alpha = *alphap;
  const float beta  = *betap;
  const int brow = tm * BM, bcol = tn * BN;
#pragma unroll
  for (int ni = 0; ni < 2; ++ni) {
    const int col = bcol + wc * 64 + ni * 32 + lr;
    const float bb = beta * (float)bias[col];
#pragma unroll
    for (int mi = 0; mi < 4; ++mi) {
      const int rbase = brow + wr * 128 + mi * 32 + 4 * hi;
#pragma unroll
      for (int r = 0; r < 16; ++r) {
        const int row = rbase + (r & 3) + 8 * (r >> 2);
        float v = alpha * (float)acc[mi][ni][r] + bb;
        v = rintf(v);
        v = fminf(127.f, fmaxf(-128.f, v));
        out[(size_t)row * N_TOT + col] = (int)v;
      }
    }
  }
}

extern "C" void kernel_launch(void* const* d_in, const int* in_sizes, int n_in,
                              void* d_out, int out_size, void* d_ws, size_t ws_size,
                              hipStream_t stream) {
  const int*   x32    = (const int*)d_in[0];   // (4,2048,4096) int8 widened to int32
  const int*   w32    = (const int*)d_in[1];   // (4096,4096)
  const int*   bias   = (const int*)d_in[2];   // (1,4096)
  const float* alphap = (const float*)d_in[3];
  const float* betap  = (const float*)d_in[4];
  int* out = (int*)d_out;

  int8_t* xp = (int8_t*)d_ws;                  // Apack: 32 MB
  int8_t* wp = xp + (size_t)M_TOT * K_TOT;     // Bpack: 16 MB (48 MB ws total)

  const int na   = (M_TOT * K_TOT) / 16;
  const int ntot = na + (N_TOT * K_TOT) / 16;
  pack_tiles<<<3072, 256, 0, stream>>>(x32, w32, xp, wp, na, ntot);

  gemm_w8a8<<<dim3((M_TOT / BM) * (N_TOT / BN)), dim3(256), 0, stream>>>(
      xp, wp, bias, alphap, betap, out);
}

// Round 9
// 203.397 us; speedup vs baseline: 1.0197x; 1.0197x over previous
//
#include <hip/hip_runtime.h>
#include <stdint.h>

using i32x4  = __attribute__((ext_vector_type(4)))  int;
using i32x16 = __attribute__((ext_vector_type(16))) int;

#define M_TOT 8192
#define N_TOT 4096
#define K_TOT 4096
#define BM 256
#define BN 256
// BK = 64 bytes; 64 K-tiles; LDS ring-3: A 3x16KB @0 | B 3x16KB @48KB = 96KB

__device__ __forceinline__ void gload_lds16(const void* g, void* l) {
  __builtin_amdgcn_global_load_lds(
      (const __attribute__((address_space(1))) void*)(uintptr_t)g,
      (__attribute__((address_space(3))) void*)(uint32_t)(uintptr_t)l,
      16, 0, 0);
}

// Repack int32-widened int8 [rows][4096] into swizzled K-chunk tiles:
// chunk (p,kc) = 16KB: [rr 0..255][64B]; physical 16B-slot sp holds logical
// slot sp ^ ((rr>>1)&3).  GEMM staging stays a pure linear copy (rule #21);
// frag ds_read applies the same XOR (throughput-optimal: 8 lanes per 4-bank
// quad, all quads parallel; residual 4cy/b128 counter is layout-invariant).
__global__ void pack_tiles(const int* __restrict__ a32, const int* __restrict__ b32,
                           int8_t* __restrict__ ap, int8_t* __restrict__ bp,
                           int na, int ntot) {
  int stride = gridDim.x * blockDim.x;
  for (int idx = blockIdx.x * blockDim.x + threadIdx.x; idx < ntot; idx += stride) {
    int i = idx;
    const int* src;
    int8_t* dst;
    if (idx < na) { src = a32; dst = ap; }
    else          { src = b32; dst = bp; i = idx - na; }
    int sp = i & 3;
    int rr = (i >> 2) & 255;
    int kc = (i >> 10) & 63;
    int p  = i >> 16;
    int sl = sp ^ ((rr >> 1) & 3);
    const i32x4* s = (const i32x4*)(src + (((size_t)(p * 256 + rr)) << 12) + kc * 64 + sl * 16);
    i32x4 a = s[0], b = s[1], c = s[2], d = s[3];
    i32x4 o;
    o.x = (a.x & 255) | ((a.y & 255) << 8) | ((a.z & 255) << 16) | (a.w << 24);
    o.y = (b.x & 255) | ((b.y & 255) << 8) | ((b.z & 255) << 16) | (b.w << 24);
    o.z = (c.x & 255) | ((c.y & 255) << 8) | ((c.z & 255) << 16) | (c.w << 24);
    o.w = (d.x & 255) | ((d.y & 255) << 8) | ((d.z & 255) << 16) | (d.w << 24);
    ((i32x4*)dst)[i] = o;
  }
}

// stage one 16KB chunk (block-wide, 2 gloads per thread)
#define STAGE_A(KC) {                                                       \
    const int8_t* _g = Asrc + (size_t)(KC) * 16384 + stoff;                 \
    char* _d = lds + ((KC) % 3) * 16384 + stoff;                            \
    gload_lds16(_g, _d); gload_lds16(_g + 8192, _d + 8192); }
#define STAGE_B(KC) {                                                       \
    const int8_t* _g = Bsrc + (size_t)(KC) * 16384 + stoff;                 \
    char* _d = lds + 49152 + ((KC) % 3) * 16384 + stoff;                    \
    gload_lds16(_g, _d); gload_lds16(_g + 8192, _d + 8192); }

// One K-tile (m201-faithful): entry counted-vmcnt + barrier, then two
// two-barrier phases {reads, stage, barrier, lgkm(0), 8 MFMA, barrier}.
// B frags are read once in phase 0 and held in registers for phase 1.
#define KTILE(RING, KC2, VM, DO_STAGE) {                                    \
    asm volatile("s_waitcnt vmcnt(" VM ")" ::: "memory");                   \
    __builtin_amdgcn_s_barrier();                                           \
    __builtin_amdgcn_sched_barrier(0);                                      \
    const char* _La = lds + (RING) * 16384;                                 \
    const char* _Lb = lds + 49152 + (RING) * 16384;                         \
    i32x4 A0[2][2], A1[2][2], B0[2][2];                                     \
    _Pragma("unroll") for (int mi = 0; mi < 2; ++mi)                        \
    _Pragma("unroll") for (int ks = 0; ks < 2; ++ks)                        \
      A0[mi][ks] = *(const i32x4*)(_La + aRow[mi] + kOff[ks]);              \
    _Pragma("unroll") for (int ni = 0; ni < 2; ++ni)                        \
    _Pragma("unroll") for (int ks = 0; ks < 2; ++ks)                        \
      B0[ni][ks] = *(const i32x4*)(_Lb + bRow[ni] + kOff[ks]);              \
    if (DO_STAGE) STAGE_A(KC2)                                              \
    __builtin_amdgcn_s_barrier();                                           \
    asm volatile("s_waitcnt lgkmcnt(0)" ::: "memory");                      \
    __builtin_amdgcn_sched_barrier(0);                                      \
    __builtin_amdgcn_s_setprio(1);                                          \
    _Pragma("unroll") for (int ks = 0; ks < 2; ++ks)                        \
    _Pragma("unroll") for (int mi = 0; mi < 2; ++mi)                        \
    _Pragma("unroll") for (int ni = 0; ni < 2; ++ni)                        \
      acc[mi][ni] = __builtin_amdgcn_mfma_i32_32x32x32_i8(A0[mi][ks], B0[ni][ks], acc[mi][ni], 0, 0, 0); \
    __builtin_amdgcn_s_setprio(0);                                          \
    __builtin_amdgcn_s_barrier();                                           \
    _Pragma("unroll") for (int mi = 0; mi < 2; ++mi)                        \
    _Pragma("unroll") for (int ks = 0; ks < 2; ++ks)                        \
      A1[mi][ks] = *(const i32x4*)(_La + aRow[mi + 2] + kOff[ks]);          \
    if (DO_STAGE) STAGE_B(KC2)                                              \
    __builtin_amdgcn_s_barrier();                                           \
    asm volatile("s_waitcnt lgkmcnt(0)" ::: "memory");                      \
    __builtin_amdgcn_sched_barrier(0);                                      \
    __builtin_amdgcn_s_setprio(1);                                          \
    _Pragma("unroll") for (int ks = 0; ks < 2; ++ks)                        \
    _Pragma("unroll") for (int mi = 0; mi < 2; ++mi)                        \
    _Pragma("unroll") for (int ni = 0; ni < 2; ++ni)                        \
      acc[mi + 2][ni] = __builtin_amdgcn_mfma_i32_32x32x32_i8(A1[mi][ks], B0[ni][ks], acc[mi + 2][ni], 0, 0, 0); \
    __builtin_amdgcn_s_setprio(0);                                          \
  }

__global__ __launch_bounds__(512, 2) void gemm_w8a8(
    const int8_t* __restrict__ Apack,  // [32 pm][64 kc][256 r][64B] swizzled
    const int8_t* __restrict__ Bpack,  // [16 pn][64 kc][256 r][64B] swizzled
    const int*    __restrict__ bias,
    const float*  __restrict__ alphap,
    const float*  __restrict__ betap,
    int* __restrict__ out)             // [M][N] int32
{
  __shared__ __align__(16) char lds[98304];  // A ring 3x16KB | B ring 3x16KB

  // XCD-aware 8x8 chunking (FETCH 270->98MB): 32 concurrent wgs/XCD share panels
  const int bid = blockIdx.x;
  const int xcd = bid & 7, wi = bid >> 3;
  const int tm = (xcd & 3) * 8 + (wi & 7);    // 0..31
  const int tn = (xcd >> 2) * 8 + (wi >> 3);  // 0..15

  const int tid = threadIdx.x;
  const int w   = tid >> 6;
  const int l   = tid & 63;
  const int lr  = l & 31;
  const int hi  = l >> 5;
  const int wr  = w >> 2;   // 0..1
  const int wc  = w & 3;    // 0..3
  const int stoff = tid * 16;

  const int8_t* Asrc = Apack + ((size_t)tm << 20);  // 64 chunks * 16KB = 1MB
  const int8_t* Bsrc = Bpack + ((size_t)tn << 20);

  const int swz = (lr >> 1) & 3;
  int aRow[4], bRow[2], kOff[2];
#pragma unroll
  for (int mi = 0; mi < 4; ++mi) aRow[mi] = (wr * 128 + mi * 32 + lr) * 64;
#pragma unroll
  for (int ni = 0; ni < 2; ++ni) bRow[ni] = (wc * 64 + ni * 32 + lr) * 64;
#pragma unroll
  for (int ks = 0; ks < 2; ++ks) kOff[ks] = ((((ks << 1) | hi)) ^ swz) * 16;

  i32x16 acc[4][2] = {};

  // prologue: stage K-tiles 0 and 1 (8 loads in flight)
  STAGE_A(0) STAGE_B(0)
  STAGE_A(1) STAGE_B(1)

  // main: k = 0..59 (ring = k%3), stage k+2 during k
  for (int t = 0; t < 20; ++t) {
    const int k = t * 3;
    KTILE(0, k + 2, "4", 1)
    KTILE(1, k + 3, "4", 1)
    KTILE(2, k + 4, "4", 1)
  }
  // tail: k=60 (stage 62), 61 (stage 63), 62 (vm4), 63 (vm0)
  KTILE(0, 62, "4", 1)
  KTILE(1, 63, "4", 1)
  KTILE(2, 0,  "4", 0)
  KTILE(0, 0,  "0", 0)

  // epilogue: y = clip(rint(alpha*acc + beta*bias)) -> int32
  // C/D 32x32 layout: col = lane&31, row = (reg&3) + 8*(reg>>2) + 4*(lane>>5)
  const float alpha = *alphap;
  const float beta  = *betap;
  const int brow = tm * BM, bcol = tn * BN;
#pragma unroll
  for (int ni = 0; ni < 2; ++ni) {
    const int col = bcol + wc * 64 + ni * 32 + lr;
    const float bb = beta * (float)bias[col];
#pragma unroll
    for (int mi = 0; mi < 4; ++mi) {
      const int rbase = brow + wr * 128 + mi * 32 + 4 * hi;
#pragma unroll
      for (int r = 0; r < 16; ++r) {
        const int row = rbase + (r & 3) + 8 * (r >> 2);
        float v = alpha * (float)acc[mi][ni][r] + bb;
        v = rintf(v);
        v = fminf(127.f, fmaxf(-128.f, v));
        out[(size_t)row * N_TOT + col] = (int)v;
      }
    }
  }
}

extern "C" void kernel_launch(void* const* d_in, const int* in_sizes, int n_in,
                              void* d_out, int out_size, void* d_ws, size_t ws_size,
                              hipStream_t stream) {
  const int*   x32    = (const int*)d_in[0];   // (4,2048,4096) int8 widened to int32
  const int*   w32    = (const int*)d_in[1];   // (4096,4096)
  const int*   bias   = (const int*)d_in[2];   // (1,4096)
  const float* alphap = (const float*)d_in[3];
  const float* betap  = (const float*)d_in[4];
  int* out = (int*)d_out;

  int8_t* xp = (int8_t*)d_ws;                  // Apack: 32 MB
  int8_t* wp = xp + (size_t)M_TOT * K_TOT;     // Bpack: 16 MB (48 MB ws total)

  const int na   = (M_TOT * K_TOT) / 16;
  const int ntot = na + (N_TOT * K_TOT) / 16;
  pack_tiles<<<3072, 256, 0, stream>>>(x32, w32, xp, wp, na, ntot);

  gemm_w8a8<<<512, 512, 0, stream>>>(xp, wp, bias, alphap, betap, out);
}

// Round 10
// 197.519 us; speedup vs baseline: 1.0500x; 1.0298x over previous
//
#include <hip/hip_runtime.h>
#include <stdint.h>

using i32x4  = __attribute__((ext_vector_type(4)))  int;
using i32x16 = __attribute__((ext_vector_type(16))) int;

#define M_TOT 8192
#define N_TOT 4096
#define K_TOT 4096
#define BM 256
#define BN 256
// BK = 64 bytes; 64 K-tiles; LDS ring-2: A 2x16KB @0 | B 2x16KB @32KB = 64KB
// Register triple-rotation: phase p MFMAs frag-set p%3, loads set (p+1)%3
// => ds_read never writes a register sourced by in-flight MFMAs (WAR-free).

__device__ __forceinline__ void gload_lds16(const void* g, void* l) {
  __builtin_amdgcn_global_load_lds(
      (const __attribute__((address_space(1))) void*)(uintptr_t)g,
      (__attribute__((address_space(3))) void*)(uint32_t)(uintptr_t)l,
      16, 0, 0);
}

// Repack int32-widened int8 [rows][4096] into swizzled K-chunk tiles:
// chunk (p,kc) = 16KB: [rr 0..255][64B]; physical 16B-slot sp holds logical
// slot sp ^ ((rr>>1)&3).  GEMM staging stays a pure linear copy (rule #21);
// frag ds_read applies the same XOR (8 lanes per 4-bank quad, all quads busy).
__global__ void pack_tiles(const int* __restrict__ a32, const int* __restrict__ b32,
                           int8_t* __restrict__ ap, int8_t* __restrict__ bp,
                           int na, int ntot) {
  int stride = gridDim.x * blockDim.x;
  for (int idx = blockIdx.x * blockDim.x + threadIdx.x; idx < ntot; idx += stride) {
    int i = idx;
    const int* src;
    int8_t* dst;
    if (idx < na) { src = a32; dst = ap; }
    else          { src = b32; dst = bp; i = idx - na; }
    int sp = i & 3;
    int rr = (i >> 2) & 255;
    int kc = (i >> 10) & 63;
    int p  = i >> 16;
    int sl = sp ^ ((rr >> 1) & 3);
    const i32x4* s = (const i32x4*)(src + (((size_t)(p * 256 + rr)) << 12) + kc * 64 + sl * 16);
    i32x4 a = s[0], b = s[1], c = s[2], d = s[3];
    i32x4 o;
    o.x = (a.x & 255) | ((a.y & 255) << 8) | ((a.z & 255) << 16) | (a.w << 24);
    o.y = (b.x & 255) | ((b.y & 255) << 8) | ((b.z & 255) << 16) | (b.w << 24);
    o.z = (c.x & 255) | ((c.y & 255) << 8) | ((c.z & 255) << 16) | (c.w << 24);
    o.w = (d.x & 255) | ((d.y & 255) << 8) | ((d.z & 255) << 16) | (d.w << 24);
    ((i32x4*)dst)[i] = o;
  }
}

// stage one 16KB chunk into LDS slot (2 gloads per thread)
#define STAGE_A(KC, SLOT) {                                                 \
    const int8_t* _g = Asrc + (size_t)(KC) * 16384 + stoff;                 \
    char* _d = lds + (SLOT) * 16384 + stoff;                                \
    gload_lds16(_g, _d); gload_lds16(_g + 8192, _d + 8192); }
#define STAGE_B(KC, SLOT) {                                                 \
    const int8_t* _g = Bsrc + (size_t)(KC) * 16384 + stoff;                 \
    char* _d = lds + 32768 + (SLOT) * 16384 + stoff;                        \
    gload_lds16(_g, _d); gload_lds16(_g + 8192, _d + 8192); }

// load one frag set (4 A + 2 B ds_read_b128) for K-step KS from LDS slot
#define LOAD_SET(FA, FB, SLOT, KS) {                                        \
    const char* _pa = lds + (SLOT) * 16384 + kOff[KS];                      \
    const char* _pb = _pa + 32768;                                          \
    FA[0] = *(const i32x4*)(_pa + aRow[0]);                                 \
    FA[1] = *(const i32x4*)(_pa + aRow[1]);                                 \
    FA[2] = *(const i32x4*)(_pa + aRow[2]);                                 \
    FA[3] = *(const i32x4*)(_pa + aRow[3]);                                 \
    FB[0] = *(const i32x4*)(_pb + bRow[0]);                                 \
    FB[1] = *(const i32x4*)(_pb + bRow[1]); }

// 8 fully independent MFMAs (one per acc register, no intra-burst chains)
#define MFMA8(FA, FB)                                                       \
    _Pragma("unroll")                                                       \
    for (int mi = 0; mi < 4; ++mi)                                          \
    _Pragma("unroll")                                                       \
    for (int ni = 0; ni < 2; ++ni)                                          \
      acc[mi][ni] = __builtin_amdgcn_mfma_i32_32x32x32_i8(FA[mi], FB[ni], acc[mi][ni], 0, 0, 0);

// K-tile k = two phases.  SA_ = set played in phase 2k (loaded last phase),
// SB_ = set loaded in phase 2k / played in 2k+1, SC_ = set loaded in 2k+1
// (tile k+1 ks0, read-ahead).  Stage(k+2) goes to tile k's own slot (ring-2);
// reads-before-barrier + stage-after-barrier makes that race-free block-wide.
// vmcnt(0) retires stage(k+1) (issued 2 phases ago, ~1400cy cover); nothing
// newer is in flight at that point, so it is a counted wait in effect.
#define KTILE(SA_, SB_, SC_, SLOT, KC2, DO_STAGE, DO_NEXT) {                \
    LOAD_SET(fA##SB_, fB##SB_, SLOT, 1)                                     \
    asm volatile("s_waitcnt vmcnt(0)" ::: "memory");                        \
    __builtin_amdgcn_s_barrier();                                           \
    __builtin_amdgcn_sched_barrier(0);                                      \
    if (DO_STAGE) { STAGE_A(KC2, SLOT) STAGE_B(KC2, SLOT) }                 \
    __builtin_amdgcn_s_setprio(1);                                          \
    MFMA8(fA##SA_, fB##SA_)                                                 \
    __builtin_amdgcn_s_setprio(0);                                          \
    if (DO_NEXT) LOAD_SET(fA##SC_, fB##SC_, (SLOT) ^ 1, 0)                  \
    __builtin_amdgcn_s_setprio(1);                                          \
    MFMA8(fA##SB_, fB##SB_)                                                 \
    __builtin_amdgcn_s_setprio(0); }

__global__ __launch_bounds__(512, 2) void gemm_w8a8(
    const int8_t* __restrict__ Apack,  // [32 pm][64 kc][256 r][64B] swizzled
    const int8_t* __restrict__ Bpack,  // [16 pn][64 kc][256 r][64B] swizzled
    const int*    __restrict__ bias,
    const float*  __restrict__ alphap,
    const float*  __restrict__ betap,
    int* __restrict__ out)             // [M][N] int32
{
  __shared__ __align__(16) char lds[65536];  // A 2x16KB | B 2x16KB

  // XCD-aware 8x8 chunking (FETCH 270->98MB): 32 concurrent wgs/XCD share panels
  const int bid = blockIdx.x;
  const int xcd = bid & 7, wi = bid >> 3;
  const int tm = (xcd & 3) * 8 + (wi & 7);    // 0..31
  const int tn = (xcd >> 2) * 8 + (wi >> 3);  // 0..15

  const int tid = threadIdx.x;
  const int w   = tid >> 6;
  const int l   = tid & 63;
  const int lr  = l & 31;
  const int hi  = l >> 5;
  const int wr  = w >> 2;   // 0..1
  const int wc  = w & 3;    // 0..3
  const int stoff = tid * 16;

  const int8_t* Asrc = Apack + ((size_t)tm << 20);  // 64 chunks * 16KB = 1MB
  const int8_t* Bsrc = Bpack + ((size_t)tn << 20);

  const int swz = (lr >> 1) & 3;
  int aRow[4], bRow[2], kOff[2];
#pragma unroll
  for (int mi = 0; mi < 4; ++mi) aRow[mi] = (wr * 128 + mi * 32 + lr) * 64;
#pragma unroll
  for (int ni = 0; ni < 2; ++ni) bRow[ni] = (wc * 64 + ni * 32 + lr) * 64;
#pragma unroll
  for (int ks = 0; ks < 2; ++ks) kOff[ks] = ((((ks << 1) | hi)) ^ swz) * 16;

  i32x16 acc[4][2] = {};
  i32x4 fA0[4], fB0[2], fA1[4], fB1[2], fA2[4], fB2[2];

  // prologue: stage tiles 0,1; retire stage(0); preload set0 = tile0 ks0
  STAGE_A(0, 0) STAGE_B(0, 0)
  STAGE_A(1, 1) STAGE_B(1, 1)
  asm volatile("s_waitcnt vmcnt(4)" ::: "memory");
  __builtin_amdgcn_s_barrier();
  __builtin_amdgcn_sched_barrier(0);
  LOAD_SET(fA0, fB0, 0, 0)

  // main: 60 tiles; set pattern period 3, slot period 2 -> unroll 6
  for (int t = 0; t < 10; ++t) {
    const int kk = t * 6;
    KTILE(0, 1, 2, 0, kk + 2, 1, 1)
    KTILE(2, 0, 1, 1, kk + 3, 1, 1)
    KTILE(1, 2, 0, 0, kk + 4, 1, 1)
    KTILE(0, 1, 2, 1, kk + 5, 1, 1)
    KTILE(2, 0, 1, 0, kk + 6, 1, 1)
    KTILE(1, 2, 0, 1, kk + 7, 1, 1)
  }
  // tail: tiles 60..63 (stages 62,63 then none; last tile no read-ahead)
  KTILE(0, 1, 2, 0, 62, 1, 1)
  KTILE(2, 0, 1, 1, 63, 1, 1)
  KTILE(1, 2, 0, 0, 0,  0, 1)
  KTILE(0, 1, 2, 1, 0,  0, 0)

  // epilogue: y = clip(rint(alpha*acc + beta*bias)) -> int32
  // C/D 32x32 layout: col = lane&31, row = (reg&3) + 8*(reg>>2) + 4*(lane>>5)
  const float alpha = *alphap;
  const float beta  = *betap;
  const int brow = tm * BM, bcol = tn * BN;
#pragma unroll
  for (int ni = 0; ni < 2; ++ni) {
    const int col = bcol + wc * 64 + ni * 32 + lr;
    const float bb = beta * (float)bias[col];
#pragma unroll
    for (int mi = 0; mi < 4; ++mi) {
      const int rbase = brow + wr * 128 + mi * 32 + 4 * hi;
#pragma unroll
      for (int r = 0; r < 16; ++r) {
        const int row = rbase + (r & 3) + 8 * (r >> 2);
        float v = alpha * (float)acc[mi][ni][r] + bb;
        v = rintf(v);
        v = fminf(127.f, fmaxf(-128.f, v));
        out[(size_t)row * N_TOT + col] = (int)v;
      }
    }
  }
}

extern "C" void kernel_launch(void* const* d_in, const int* in_sizes, int n_in,
                              void* d_out, int out_size, void* d_ws, size_t ws_size,
                              hipStream_t stream) {
  const int*   x32    = (const int*)d_in[0];   // (4,2048,4096) int8 widened to int32
  const int*   w32    = (const int*)d_in[1];   // (4096,4096)
  const int*   bias   = (const int*)d_in[2];   // (1,4096)
  const float* alphap = (const float*)d_in[3];
  const float* betap  = (const float*)d_in[4];
  int* out = (int*)d_out;

  int8_t* xp = (int8_t*)d_ws;                  // Apack: 32 MB
  int8_t* wp = xp + (size_t)M_TOT * K_TOT;     // Bpack: 16 MB (48 MB ws total)

  const int na   = (M_TOT * K_TOT) / 16;
  const int ntot = na + (N_TOT * K_TOT) / 16;
  pack_tiles<<<3072, 256, 0, stream>>>(x32, w32, xp, wp, na, ntot);

  gemm_w8a8<<<512, 512, 0, stream>>>(xp, wp, bias, alphap, betap, out);
}